// Round 1
// baseline (818.502 us; speedup 1.0000x reference)
//
#include <hip/hip_runtime.h>

#define N_USER 50000
#define N_ITEM 100000
#define NTOT   150000
#define D      64
#define NNZ    2400000
#define BQ     4096
#define NEG_SLOPE 0.01f

// ---------------- concat user+item embeddings into ego0 ----------------
__global__ void k_concat(const float* __restrict__ u, const float* __restrict__ it,
                         float* __restrict__ A) {
    int i = blockIdx.x * 256 + threadIdx.x;          // float4 index, exact grid
    const int nu4 = N_USER * D / 4;
    float4 v;
    if (i < nu4) v = ((const float4*)u)[i];
    else         v = ((const float4*)it)[i - nu4];
    ((float4*)A)[i] = v;
}

__global__ void k_zero(int* __restrict__ p, int n) {
    int i = blockIdx.x * 256 + threadIdx.x;
    if (i < n) p[i] = 0;
}

__global__ void k_hist(const int* __restrict__ rows, int* __restrict__ cnt) {
    int i = blockIdx.x * 256 + threadIdx.x;          // exact grid == NNZ
    atomicAdd(&cnt[rows[i]], 1);
}

// ---------------- 2-level exclusive scan over 150000 counts ----------------
__global__ void k_scanA(const int* __restrict__ cnt, int* __restrict__ ptr,
                        int* __restrict__ bsums, int n) {
    __shared__ int s[1024];
    int tid = threadIdx.x;
    int gid = blockIdx.x * 1024 + tid;
    int v = (gid < n) ? cnt[gid] : 0;
    s[tid] = v; __syncthreads();
    for (int off = 1; off < 1024; off <<= 1) {
        int t = (tid >= off) ? s[tid - off] : 0;
        __syncthreads();
        s[tid] += t;
        __syncthreads();
    }
    if (gid < n) ptr[gid + 1] = s[tid];              // block-local inclusive
    if (tid == 1023) bsums[blockIdx.x] = s[1023];
}

__global__ void k_scanB(int* __restrict__ bsums, int nb) {
    __shared__ int s[256];
    int tid = threadIdx.x;
    int v = (tid < nb) ? bsums[tid] : 0;
    s[tid] = v; __syncthreads();
    for (int off = 1; off < 256; off <<= 1) {
        int t = (tid >= off) ? s[tid - off] : 0;
        __syncthreads();
        s[tid] += t;
        __syncthreads();
    }
    if (tid < nb) bsums[tid] = s[tid] - v;           // exclusive
}

__global__ void k_scanC(int* __restrict__ ptr, int* __restrict__ cnt_cursor,
                        const int* __restrict__ bsums, int n) {
    int tid = threadIdx.x;
    int gid = blockIdx.x * 1024 + tid;
    if (gid == 0) ptr[0] = 0;
    if (gid < n) {
        int c   = cnt_cursor[gid];
        int inc = ptr[gid + 1] + bsums[blockIdx.x];  // final inclusive prefix
        ptr[gid + 1] = inc;
        cnt_cursor[gid] = inc - c;                   // exclusive start == cursor
    }
}

__global__ void k_scatter(const int* __restrict__ rows, const int* __restrict__ cols,
                          const float* __restrict__ vals, int* __restrict__ cursor,
                          int2* __restrict__ csr) {
    int i = blockIdx.x * 256 + threadIdx.x;          // exact grid == NNZ
    int r = rows[i];
    int p = atomicAdd(&cursor[r], 1);
    csr[p] = make_int2(cols[i], __float_as_int(vals[i]));
}

// ---------------- SpMM: one wave per row, lanes = D columns ----------------
__global__ __launch_bounds__(256) void k_spmm(const int* __restrict__ ptr,
                                              const int2* __restrict__ csr,
                                              const float* __restrict__ E,
                                              float* __restrict__ Lout) {
    int lane = threadIdx.x & 63;
    int r = blockIdx.x * 4 + (threadIdx.x >> 6);
    int start = ptr[r], end = ptr[r + 1];
    float acc = 0.f;
    for (int j0 = start; j0 < end; j0 += 64) {
        int m = end - j0; if (m > 64) m = 64;
        int2 e = (lane < m) ? csr[j0 + lane] : make_int2(0, 0);
        int t = 0;
        for (; t + 3 < m; t += 4) {                  // 4x unroll -> 4 loads in flight
            int   c0 = __shfl(e.x, t, 64),     c1 = __shfl(e.x, t + 1, 64);
            int   c2 = __shfl(e.x, t + 2, 64), c3 = __shfl(e.x, t + 3, 64);
            float v0 = __int_as_float(__shfl(e.y, t, 64));
            float v1 = __int_as_float(__shfl(e.y, t + 1, 64));
            float v2 = __int_as_float(__shfl(e.y, t + 2, 64));
            float v3 = __int_as_float(__shfl(e.y, t + 3, 64));
            float g0 = E[c0 * D + lane];
            float g1 = E[c1 * D + lane];
            float g2 = E[c2 * D + lane];
            float g3 = E[c3 * D + lane];
            acc += v0 * g0; acc += v1 * g1; acc += v2 * g2; acc += v3 * g3;
        }
        for (; t < m; ++t) {
            int   c = __shfl(e.x, t, 64);
            float v = __int_as_float(__shfl(e.y, t, 64));
            acc += v * E[c * D + lane];
        }
    }
    Lout[r * D + lane] = acc;
}

// ---- fused transform: ego_new = leaky((L+E)@Wgc + (L*E)@Wbi + 2b), in-place over L ----
__global__ __launch_bounds__(256) void k_transform(const float* __restrict__ A,
                                                   float* __restrict__ B,
                                                   const float* __restrict__ Wgc,
                                                   const float* __restrict__ Wbi,
                                                   const float* __restrict__ bb, int n) {
    __shared__ float xT[2 * D][D];   // [k][row], 32KB
    __shared__ float W2[2 * D][D];   // [k][col], 32KB  (Wgc on top of Wbi)
    int tid = threadIdx.x;
    int rowbase = blockIdx.x * 64;

    // stage W: 128x64 floats = 2048 float4
    for (int i = tid; i < 128 * 16; i += 256) {
        int k = i >> 4, q = i & 15;
        const float* src = (k < D) ? (Wgc + k * D + q * 4) : (Wbi + (k - D) * D + q * 4);
        *(float4*)&W2[k][q * 4] = *(const float4*)src;
    }
    // stage x1 = L + E (k in [0,64)), x2 = L * E (k in [64,128)), transposed
    {
        int row = tid >> 2;
        int cg  = (tid & 3) * 16;
        int r   = rowbase + row;
        for (int j = 0; j < 4; ++j) {
            int c = cg + j * 4;
            float4 l = make_float4(0, 0, 0, 0), e = make_float4(0, 0, 0, 0);
            if (r < n) {
                l = *(const float4*)&B[r * D + c];
                e = *(const float4*)&A[r * D + c];
            }
            xT[c + 0][row] = l.x + e.x;  xT[D + c + 0][row] = l.x * e.x;
            xT[c + 1][row] = l.y + e.y;  xT[D + c + 1][row] = l.y * e.y;
            xT[c + 2][row] = l.z + e.z;  xT[D + c + 2][row] = l.z * e.z;
            xT[c + 3][row] = l.w + e.w;  xT[D + c + 3][row] = l.w * e.w;
        }
    }
    __syncthreads();

    int tx = tid & 15, ty = tid >> 4;          // 4 cols per tx, 4 rows per ty
    float acc[4][4];
    #pragma unroll
    for (int i = 0; i < 4; ++i)
        #pragma unroll
        for (int j = 0; j < 4; ++j) acc[i][j] = 0.f;

    #pragma unroll 4
    for (int k = 0; k < 2 * D; ++k) {
        float4 a = *(const float4*)&xT[k][ty * 4];
        float4 b = *(const float4*)&W2[k][tx * 4];
        float av[4] = {a.x, a.y, a.z, a.w};
        float bv[4] = {b.x, b.y, b.z, b.w};
        #pragma unroll
        for (int i = 0; i < 4; ++i)
            #pragma unroll
            for (int j = 0; j < 4; ++j) acc[i][j] += av[i] * bv[j];
    }

    float4 bias = *(const float4*)&bb[tx * 4];
    float bv[4] = {bias.x, bias.y, bias.z, bias.w};
    #pragma unroll
    for (int i = 0; i < 4; ++i) {
        int r = rowbase + ty * 4 + i;
        if (r < n) {
            float o[4];
            #pragma unroll
            for (int j = 0; j < 4; ++j) {
                float y = acc[i][j] + 2.f * bv[j];
                o[j] = (y >= 0.f) ? y : NEG_SLOPE * y;
            }
            *(float4*)&B[r * D + tx * 4] = make_float4(o[0], o[1], o[2], o[3]);
        }
    }
}

// ---------------- gathers into output ----------------
__global__ void k_gather0(const float* __restrict__ A, const int* __restrict__ users,
                          const int* __restrict__ pos, const int* __restrict__ neg,
                          float* __restrict__ out) {
    int lane = threadIdx.x & 63;
    int gi = blockIdx.x * 4 + (threadIdx.x >> 6);
    int g = gi >> 12, b = gi & 4095;
    int src = (g == 0) ? users[b] : (N_USER + ((g == 1) ? pos[b] : neg[b]));
    out[gi * 256 + lane] = A[src * D + lane];
}

__global__ void k_gathern(const float* __restrict__ E, const int* __restrict__ users,
                          const int* __restrict__ pos, const int* __restrict__ neg,
                          float* __restrict__ out, int layer) {
    int lane = threadIdx.x & 63;
    int gi = blockIdx.x * 4 + (threadIdx.x >> 6);
    int g = gi >> 12, b = gi & 4095;
    int src = (g == 0) ? users[b] : (N_USER + ((g == 1) ? pos[b] : neg[b]));
    float v = E[src * D + lane];
    float ss = v * v;
    #pragma unroll
    for (int off = 32; off >= 1; off >>= 1) ss += __shfl_xor(ss, off, 64);
    float dnm = fmaxf(sqrtf(ss), 1e-12f);
    out[gi * 256 + layer * D + lane] = v / dnm;
}

extern "C" void kernel_launch(void* const* d_in, const int* in_sizes, int n_in,
                              void* d_out, int out_size, void* d_ws, size_t ws_size,
                              hipStream_t stream) {
    const float* user_emb = (const float*)d_in[0];
    const float* item_emb = (const float*)d_in[1];
    const float* W_gc     = (const float*)d_in[2];
    const float* W_bi     = (const float*)d_in[3];
    const float* b_bi     = (const float*)d_in[4];
    const float* vals     = (const float*)d_in[5];
    const int*   rows     = (const int*)d_in[6];
    const int*   cols     = (const int*)d_in[7];
    const int*   users    = (const int*)d_in[8];
    const int*   pos      = (const int*)d_in[9];
    const int*   neg      = (const int*)d_in[10];
    float* out = (float*)d_out;

    char* ws = (char*)d_ws;
    size_t off = 0;
    auto alloc = [&](size_t b) { void* p = ws + off; off += (b + 255) & ~(size_t)255; return p; };
    float* A      = (float*)alloc((size_t)NTOT * D * 4);
    float* Bb     = (float*)alloc((size_t)NTOT * D * 4);
    int2*  csr    = (int2*) alloc((size_t)NNZ * 8);
    int*   ptr    = (int*)  alloc((size_t)(NTOT + 1) * 4);
    int*   cursor = (int*)  alloc((size_t)NTOT * 4);
    int*   bsums  = (int*)  alloc(1024 * 4);
    (void)ws_size;

    hipLaunchKernelGGL(k_concat,  dim3(9375), dim3(256), 0, stream, user_emb, item_emb, A);
    hipLaunchKernelGGL(k_zero,    dim3(586),  dim3(256), 0, stream, cursor, NTOT);
    hipLaunchKernelGGL(k_hist,    dim3(9375), dim3(256), 0, stream, rows, cursor);
    hipLaunchKernelGGL(k_scanA,   dim3(147),  dim3(1024), 0, stream, cursor, ptr, bsums, NTOT);
    hipLaunchKernelGGL(k_scanB,   dim3(1),    dim3(256), 0, stream, bsums, 147);
    hipLaunchKernelGGL(k_scanC,   dim3(147),  dim3(1024), 0, stream, ptr, cursor, bsums, NTOT);
    hipLaunchKernelGGL(k_scatter, dim3(9375), dim3(256), 0, stream, rows, cols, vals, cursor, csr);
    hipLaunchKernelGGL(k_gather0, dim3(3072), dim3(256), 0, stream, A, users, pos, neg, out);

    float* cur = A; float* nxt = Bb;
    for (int k = 0; k < 3; ++k) {
        hipLaunchKernelGGL(k_spmm,      dim3(37500), dim3(256), 0, stream, ptr, csr, cur, nxt);
        hipLaunchKernelGGL(k_transform, dim3(2344),  dim3(256), 0, stream, cur, nxt,
                           W_gc + k * 4096, W_bi + k * 4096, b_bi + k * 64, NTOT);
        hipLaunchKernelGGL(k_gathern,   dim3(3072),  dim3(256), 0, stream, nxt, users, pos, neg, out, k + 1);
        float* t = cur; cur = nxt; nxt = t;
    }
}

// Round 2
// 622.386 us; speedup vs baseline: 1.3151x; 1.3151x over previous
//
#include <hip/hip_runtime.h>

#define N_USER 50000
#define N_ITEM 100000
#define NTOT   150000
#define D      64
#define NNZ    2400000
#define NEG_SLOPE 0.01f

#define BSHIFT 10
#define NB     147            // ceil(NTOT / 1024)
#define P1_PER 16384          // entries per block in binning passes (1024 thr x 16)

// ---------------- concat user+item embeddings into ego0 ----------------
__global__ void k_concat(const float* __restrict__ u, const float* __restrict__ it,
                         float* __restrict__ A) {
    int i = blockIdx.x * 256 + threadIdx.x;          // float4 index, exact grid
    const int nu4 = N_USER * D / 4;
    float4 v;
    if (i < nu4) v = ((const float4*)u)[i];
    else         v = ((const float4*)it)[i - nu4];
    ((float4*)A)[i] = v;
}

__global__ void k_bzero(int* __restrict__ bcnt) {
    int t = threadIdx.x;
    if (t < NB) bcnt[t] = 0;
}

// ---------------- bucket histogram (LDS-aggregated) ----------------
__global__ __launch_bounds__(1024) void k_bhist(const int* __restrict__ rows,
                                                int* __restrict__ bcnt) {
    __shared__ int lcnt[NB];
    int tid = threadIdx.x;
    if (tid < NB) lcnt[tid] = 0;
    __syncthreads();
    int base = blockIdx.x * P1_PER;
    #pragma unroll
    for (int k = 0; k < 16; ++k) {
        int i = base + k * 1024 + tid;
        if (i < NNZ) atomicAdd(&lcnt[rows[i] >> BSHIFT], 1);
    }
    __syncthreads();
    if (tid < NB) atomicAdd(&bcnt[tid], lcnt[tid]);
}

__global__ void k_bscan(const int* __restrict__ bcnt, int* __restrict__ bptr,
                        int* __restrict__ bcur) {
    __shared__ int s[256];
    int tid = threadIdx.x;
    int v = (tid < NB) ? bcnt[tid] : 0;
    s[tid] = v; __syncthreads();
    for (int off = 1; off < 256; off <<= 1) {
        int t = (tid >= off) ? s[tid - off] : 0;
        __syncthreads();
        s[tid] += t;
        __syncthreads();
    }
    if (tid < NB) { int ex = s[tid] - v; bptr[tid] = ex; bcur[tid] = ex; }
    if (tid == NB - 1) bptr[NB] = s[tid];
}

// ---------------- pass 1: bin entries bucket-major (coalesced runs) ----------------
__global__ __launch_bounds__(1024) void k_binpass1(const int* __restrict__ rows,
                                                   const int* __restrict__ cols,
                                                   const float* __restrict__ vals,
                                                   int* __restrict__ bcur,
                                                   int2* __restrict__ bucketed) {
    __shared__ int lcnt[NB], lbase[NB];
    int tid = threadIdx.x;
    int base = blockIdx.x * P1_PER;
    if (tid < NB) lcnt[tid] = 0;
    __syncthreads();
    int r[16];
    #pragma unroll
    for (int k = 0; k < 16; ++k) {
        int i = base + k * 1024 + tid;
        r[k] = (i < NNZ) ? rows[i] : -1;
        if (r[k] >= 0) atomicAdd(&lcnt[r[k] >> BSHIFT], 1);
    }
    __syncthreads();
    if (tid < NB) { lbase[tid] = atomicAdd(&bcur[tid], lcnt[tid]); lcnt[tid] = 0; }
    __syncthreads();
    #pragma unroll
    for (int k = 0; k < 16; ++k) {
        int i = base + k * 1024 + tid;
        if (r[k] >= 0) {
            int b = r[k] >> BSHIFT;
            int off = atomicAdd(&lcnt[b], 1);
            bucketed[lbase[b] + off] =
                make_int2(((r[k] & 1023) << 18) | cols[i], __float_as_int(vals[i]));
        }
    }
}

// ---------------- pass 2: per-bucket CSR build (ptr + in-bucket scatter) ----------------
__global__ __launch_bounds__(1024) void k_binpass2(const int* __restrict__ bptr,
                                                   const int2* __restrict__ bucketed,
                                                   int* __restrict__ ptr,
                                                   int2* __restrict__ csr) {
    __shared__ int c0[1024], px[1024];
    int tid = threadIdx.x, b = blockIdx.x;
    int s = bptr[b], e = bptr[b + 1];
    c0[tid] = 0;
    __syncthreads();
    for (int i = s + tid; i < e; i += 1024) atomicAdd(&c0[bucketed[i].x >> 18], 1);
    __syncthreads();
    int v = c0[tid];
    px[tid] = v;
    __syncthreads();
    for (int off = 1; off < 1024; off <<= 1) {
        int t = (tid >= off) ? px[tid - off] : 0;
        __syncthreads();
        px[tid] += t;
        __syncthreads();
    }
    int ex = px[tid] - v;                         // exclusive prefix within bucket
    int r = (b << BSHIFT) + tid;
    if (r <= NTOT) ptr[r] = s + ex;               // covers ptr[NTOT]=NNZ at b=146,tid=496
    px[tid] = ex;
    c0[tid] = 0;
    __syncthreads();
    for (int i = s + tid; i < e; i += 1024) {
        int2 e2 = bucketed[i];
        int lr = e2.x >> 18;
        int off = atomicAdd(&c0[lr], 1);
        csr[s + px[lr] + off] = make_int2(e2.x & 0x3FFFF, e2.y);
    }
}

// ---------------- SpMM: one wave per row, lanes = D columns ----------------
__global__ __launch_bounds__(256) void k_spmm(const int* __restrict__ ptr,
                                              const int2* __restrict__ csr,
                                              const float* __restrict__ E,
                                              float* __restrict__ Lout) {
    int lane = threadIdx.x & 63;
    int r = blockIdx.x * 4 + (threadIdx.x >> 6);
    int start = ptr[r], end = ptr[r + 1];
    float acc = 0.f;
    for (int j0 = start; j0 < end; j0 += 64) {
        int m = end - j0; if (m > 64) m = 64;
        int2 e = (lane < m) ? csr[j0 + lane] : make_int2(0, 0);
        int t = 0;
        for (; t + 3 < m; t += 4) {
            int   c0 = __shfl(e.x, t, 64),     c1 = __shfl(e.x, t + 1, 64);
            int   c2 = __shfl(e.x, t + 2, 64), c3 = __shfl(e.x, t + 3, 64);
            float v0 = __int_as_float(__shfl(e.y, t, 64));
            float v1 = __int_as_float(__shfl(e.y, t + 1, 64));
            float v2 = __int_as_float(__shfl(e.y, t + 2, 64));
            float v3 = __int_as_float(__shfl(e.y, t + 3, 64));
            float g0 = E[c0 * D + lane];
            float g1 = E[c1 * D + lane];
            float g2 = E[c2 * D + lane];
            float g3 = E[c3 * D + lane];
            acc += v0 * g0; acc += v1 * g1; acc += v2 * g2; acc += v3 * g3;
        }
        for (; t < m; ++t) {
            int   c = __shfl(e.x, t, 64);
            float v = __int_as_float(__shfl(e.y, t, 64));
            acc += v * E[c * D + lane];
        }
    }
    Lout[r * D + lane] = acc;
}

// ---- fused transform: ego_new = leaky((L+E)@Wgc + (L*E)@Wbi + 2b), in-place over L ----
__global__ __launch_bounds__(256) void k_transform(const float* __restrict__ A,
                                                   float* __restrict__ B,
                                                   const float* __restrict__ Wgc,
                                                   const float* __restrict__ Wbi,
                                                   const float* __restrict__ bb, int n) {
    __shared__ float xT[2 * D][D];
    __shared__ float W2[2 * D][D];
    int tid = threadIdx.x;
    int rowbase = blockIdx.x * 64;

    for (int i = tid; i < 128 * 16; i += 256) {
        int k = i >> 4, q = i & 15;
        const float* src = (k < D) ? (Wgc + k * D + q * 4) : (Wbi + (k - D) * D + q * 4);
        *(float4*)&W2[k][q * 4] = *(const float4*)src;
    }
    {
        int row = tid >> 2;
        int cg  = (tid & 3) * 16;
        int r   = rowbase + row;
        for (int j = 0; j < 4; ++j) {
            int c = cg + j * 4;
            float4 l = make_float4(0, 0, 0, 0), e = make_float4(0, 0, 0, 0);
            if (r < n) {
                l = *(const float4*)&B[r * D + c];
                e = *(const float4*)&A[r * D + c];
            }
            xT[c + 0][row] = l.x + e.x;  xT[D + c + 0][row] = l.x * e.x;
            xT[c + 1][row] = l.y + e.y;  xT[D + c + 1][row] = l.y * e.y;
            xT[c + 2][row] = l.z + e.z;  xT[D + c + 2][row] = l.z * e.z;
            xT[c + 3][row] = l.w + e.w;  xT[D + c + 3][row] = l.w * e.w;
        }
    }
    __syncthreads();

    int tx = tid & 15, ty = tid >> 4;
    float acc[4][4];
    #pragma unroll
    for (int i = 0; i < 4; ++i)
        #pragma unroll
        for (int j = 0; j < 4; ++j) acc[i][j] = 0.f;

    #pragma unroll 4
    for (int k = 0; k < 2 * D; ++k) {
        float4 a = *(const float4*)&xT[k][ty * 4];
        float4 b = *(const float4*)&W2[k][tx * 4];
        float av[4] = {a.x, a.y, a.z, a.w};
        float bv[4] = {b.x, b.y, b.z, b.w};
        #pragma unroll
        for (int i = 0; i < 4; ++i)
            #pragma unroll
            for (int j = 0; j < 4; ++j) acc[i][j] += av[i] * bv[j];
    }

    float4 bias = *(const float4*)&bb[tx * 4];
    float bv[4] = {bias.x, bias.y, bias.z, bias.w};
    #pragma unroll
    for (int i = 0; i < 4; ++i) {
        int r = rowbase + ty * 4 + i;
        if (r < n) {
            float o[4];
            #pragma unroll
            for (int j = 0; j < 4; ++j) {
                float y = acc[i][j] + 2.f * bv[j];
                o[j] = (y >= 0.f) ? y : NEG_SLOPE * y;
            }
            *(float4*)&B[r * D + tx * 4] = make_float4(o[0], o[1], o[2], o[3]);
        }
    }
}

// ---------------- gathers into output ----------------
__global__ void k_gather0(const float* __restrict__ A, const int* __restrict__ users,
                          const int* __restrict__ pos, const int* __restrict__ neg,
                          float* __restrict__ out) {
    int lane = threadIdx.x & 63;
    int gi = blockIdx.x * 4 + (threadIdx.x >> 6);
    int g = gi >> 12, b = gi & 4095;
    int src = (g == 0) ? users[b] : (N_USER + ((g == 1) ? pos[b] : neg[b]));
    out[gi * 256 + lane] = A[src * D + lane];
}

__global__ void k_gathern(const float* __restrict__ E, const int* __restrict__ users,
                          const int* __restrict__ pos, const int* __restrict__ neg,
                          float* __restrict__ out, int layer) {
    int lane = threadIdx.x & 63;
    int gi = blockIdx.x * 4 + (threadIdx.x >> 6);
    int g = gi >> 12, b = gi & 4095;
    int src = (g == 0) ? users[b] : (N_USER + ((g == 1) ? pos[b] : neg[b]));
    float v = E[src * D + lane];
    float ss = v * v;
    #pragma unroll
    for (int off = 32; off >= 1; off >>= 1) ss += __shfl_xor(ss, off, 64);
    float dnm = fmaxf(sqrtf(ss), 1e-12f);
    out[gi * 256 + layer * D + lane] = v / dnm;
}

extern "C" void kernel_launch(void* const* d_in, const int* in_sizes, int n_in,
                              void* d_out, int out_size, void* d_ws, size_t ws_size,
                              hipStream_t stream) {
    const float* user_emb = (const float*)d_in[0];
    const float* item_emb = (const float*)d_in[1];
    const float* W_gc     = (const float*)d_in[2];
    const float* W_bi     = (const float*)d_in[3];
    const float* b_bi     = (const float*)d_in[4];
    const float* vals     = (const float*)d_in[5];
    const int*   rows     = (const int*)d_in[6];
    const int*   cols     = (const int*)d_in[7];
    const int*   users    = (const int*)d_in[8];
    const int*   pos      = (const int*)d_in[9];
    const int*   neg      = (const int*)d_in[10];
    float* out = (float*)d_out;

    char* ws = (char*)d_ws;
    size_t off = 0;
    auto alloc = [&](size_t b) { void* p = ws + off; off += (b + 255) & ~(size_t)255; return p; };
    float* A    = (float*)alloc((size_t)NTOT * D * 4);
    float* Bb   = (float*)alloc((size_t)NTOT * D * 4);
    int2*  csr  = (int2*) alloc((size_t)NNZ * 8);
    int*   ptr  = (int*)  alloc((size_t)(NTOT + 1) * 4);
    int*   bptr = (int*)  alloc((NB + 1) * 4);
    int*   bcnt = (int*)  alloc(NB * 4);
    int*   bcur = (int*)  alloc(NB * 4);
    int2*  bucketed = (int2*)Bb;   // alias: Bb unused until first spmm, bucketed dead after pass2
    (void)ws_size;

    hipLaunchKernelGGL(k_concat,   dim3(9375), dim3(256),  0, stream, user_emb, item_emb, A);
    hipLaunchKernelGGL(k_bzero,    dim3(1),    dim3(256),  0, stream, bcnt);
    hipLaunchKernelGGL(k_bhist,    dim3(NB),   dim3(1024), 0, stream, rows, bcnt);
    hipLaunchKernelGGL(k_bscan,    dim3(1),    dim3(256),  0, stream, bcnt, bptr, bcur);
    hipLaunchKernelGGL(k_binpass1, dim3(NB),   dim3(1024), 0, stream, rows, cols, vals, bcur, bucketed);
    hipLaunchKernelGGL(k_binpass2, dim3(NB),   dim3(1024), 0, stream, bptr, bucketed, ptr, csr);
    hipLaunchKernelGGL(k_gather0,  dim3(3072), dim3(256),  0, stream, A, users, pos, neg, out);

    float* cur = A; float* nxt = Bb;
    for (int k = 0; k < 3; ++k) {
        hipLaunchKernelGGL(k_spmm,      dim3(37500), dim3(256), 0, stream, ptr, csr, cur, nxt);
        hipLaunchKernelGGL(k_transform, dim3(2344),  dim3(256), 0, stream, cur, nxt,
                           W_gc + k * 4096, W_bi + k * 4096, b_bi + k * 64, NTOT);
        hipLaunchKernelGGL(k_gathern,   dim3(3072),  dim3(256), 0, stream, nxt, users, pos, neg, out, k + 1);
        float* t = cur; cur = nxt; nxt = t;
    }
}

// Round 3
// 558.453 us; speedup vs baseline: 1.4657x; 1.1145x over previous
//
#include <hip/hip_runtime.h>

#define N_USER 50000
#define N_ITEM 100000
#define NTOT   150000
#define D      64
#define NNZ    2400000
#define NEG_SLOPE 0.01f

#define BSHIFT 10
#define NB     147            // ceil(NTOT / 1024)
#define P1_PER 16384          // entries per block in binning passes (1024 thr x 16)

typedef unsigned int uint;
typedef unsigned short ushort;

__device__ inline uint bf16rne(float x) {           // f32 -> bf16 bits (RNE)
    uint b = __float_as_uint(x);
    return (b + 0x7FFFu + ((b >> 16) & 1u)) >> 16;
}
__device__ inline float bf_lo(uint u) { return __uint_as_float(u << 16); }
__device__ inline float bf_hi(uint u) { return __uint_as_float(u & 0xFFFF0000u); }

// ---------------- concat user+item embeddings -> bf16 ego0 ----------------
__global__ void k_concat16(const float* __restrict__ u, const float* __restrict__ it,
                           ushort* __restrict__ A16) {
    int i = blockIdx.x * 256 + threadIdx.x;          // float4 index, exact grid 2.4M
    const int nu4 = N_USER * D / 4;
    float4 v = (i < nu4) ? ((const float4*)u)[i] : ((const float4*)it)[i - nu4];
    uint lo = bf16rne(v.x) | (bf16rne(v.y) << 16);
    uint hi = bf16rne(v.z) | (bf16rne(v.w) << 16);
    ((uint2*)A16)[i] = make_uint2(lo, hi);
}

__global__ void k_bzero(int* __restrict__ bcnt) {
    int t = threadIdx.x;
    if (t < NB) bcnt[t] = 0;
}

// ---------------- bucket histogram (LDS-aggregated) ----------------
__global__ __launch_bounds__(1024) void k_bhist(const int* __restrict__ rows,
                                                int* __restrict__ bcnt) {
    __shared__ int lcnt[NB];
    int tid = threadIdx.x;
    if (tid < NB) lcnt[tid] = 0;
    __syncthreads();
    int base = blockIdx.x * P1_PER;
    #pragma unroll
    for (int k = 0; k < 16; ++k) {
        int i = base + k * 1024 + tid;
        if (i < NNZ) atomicAdd(&lcnt[rows[i] >> BSHIFT], 1);
    }
    __syncthreads();
    if (tid < NB) atomicAdd(&bcnt[tid], lcnt[tid]);
}

__global__ void k_bscan(const int* __restrict__ bcnt, int* __restrict__ bptr,
                        int* __restrict__ bcur) {
    __shared__ int s[256];
    int tid = threadIdx.x;
    int v = (tid < NB) ? bcnt[tid] : 0;
    s[tid] = v; __syncthreads();
    for (int off = 1; off < 256; off <<= 1) {
        int t = (tid >= off) ? s[tid - off] : 0;
        __syncthreads();
        s[tid] += t;
        __syncthreads();
    }
    if (tid < NB) { int ex = s[tid] - v; bptr[tid] = ex; bcur[tid] = ex; }
    if (tid == NB - 1) bptr[NB] = s[tid];
}

// ---------------- pass 1: bin entries bucket-major ----------------
__global__ __launch_bounds__(1024) void k_binpass1(const int* __restrict__ rows,
                                                   const int* __restrict__ cols,
                                                   const float* __restrict__ vals,
                                                   int* __restrict__ bcur,
                                                   int2* __restrict__ bucketed) {
    __shared__ int lcnt[NB], lbase[NB];
    int tid = threadIdx.x;
    int base = blockIdx.x * P1_PER;
    if (tid < NB) lcnt[tid] = 0;
    __syncthreads();
    int r[16];
    #pragma unroll
    for (int k = 0; k < 16; ++k) {
        int i = base + k * 1024 + tid;
        r[k] = (i < NNZ) ? rows[i] : -1;
        if (r[k] >= 0) atomicAdd(&lcnt[r[k] >> BSHIFT], 1);
    }
    __syncthreads();
    if (tid < NB) { lbase[tid] = atomicAdd(&bcur[tid], lcnt[tid]); lcnt[tid] = 0; }
    __syncthreads();
    #pragma unroll
    for (int k = 0; k < 16; ++k) {
        int i = base + k * 1024 + tid;
        if (r[k] >= 0) {
            int b = r[k] >> BSHIFT;
            int off = atomicAdd(&lcnt[b], 1);
            bucketed[lbase[b] + off] =
                make_int2(((r[k] & 1023) << 18) | cols[i], __float_as_int(vals[i]));
        }
    }
}

// ---------------- pass 2: per-bucket CSR build ----------------
__global__ __launch_bounds__(1024) void k_binpass2(const int* __restrict__ bptr,
                                                   const int2* __restrict__ bucketed,
                                                   int* __restrict__ ptr,
                                                   int2* __restrict__ csr) {
    __shared__ int c0[1024], px[1024];
    int tid = threadIdx.x, b = blockIdx.x;
    int s = bptr[b], e = bptr[b + 1];
    c0[tid] = 0;
    __syncthreads();
    for (int i = s + tid; i < e; i += 1024) atomicAdd(&c0[bucketed[i].x >> 18], 1);
    __syncthreads();
    int v = c0[tid];
    px[tid] = v;
    __syncthreads();
    for (int off = 1; off < 1024; off <<= 1) {
        int t = (tid >= off) ? px[tid - off] : 0;
        __syncthreads();
        px[tid] += t;
        __syncthreads();
    }
    int ex = px[tid] - v;
    int r = (b << BSHIFT) + tid;
    if (r <= NTOT) ptr[r] = s + ex;
    px[tid] = ex;
    c0[tid] = 0;
    __syncthreads();
    for (int i = s + tid; i < e; i += 1024) {
        int2 e2 = bucketed[i];
        int lr = e2.x >> 18;
        int off = atomicAdd(&c0[lr], 1);
        csr[s + px[lr] + off] = make_int2(e2.x & 0x3FFFF, e2.y);
    }
}

// -------- SpMM: one wave per row, 2 entries/iter, bf16 gathers, f32 accum --------
__global__ __launch_bounds__(256) void k_spmm(const int* __restrict__ ptr,
                                              const int2* __restrict__ csr,
                                              const ushort* __restrict__ E16,
                                              float* __restrict__ Lout) {
    int lane = threadIdx.x & 63;
    int half = lane >> 5;
    int l32  = lane & 31;
    int r = blockIdx.x * 4 + (threadIdx.x >> 6);
    int start = ptr[r], end = ptr[r + 1];
    float acc0 = 0.f, acc1 = 0.f;
    const uint* E32 = (const uint*)E16;              // [c*32 + l32] = cols (2*l32, 2*l32+1)
    for (int j0 = start; j0 < end; j0 += 64) {
        int m = end - j0; if (m > 64) m = 64;
        int2 e = (lane < m) ? csr[j0 + lane] : make_int2(0, 0);
        int t = 0;
        for (; t + 3 < m; t += 4) {                  // 4 entries, 2 per half, 2 loads in flight
            int   cA = __shfl(e.x, t + half, 64);
            int   cB = __shfl(e.x, t + 2 + half, 64);
            float vA = __int_as_float(__shfl(e.y, t + half, 64));
            float vB = __int_as_float(__shfl(e.y, t + 2 + half, 64));
            uint uA = E32[cA * 32 + l32];
            uint uB = E32[cB * 32 + l32];
            acc0 += vA * bf_lo(uA);  acc1 += vA * bf_hi(uA);
            acc0 += vB * bf_lo(uB);  acc1 += vB * bf_hi(uB);
        }
        for (; t + 1 < m; t += 2) {
            int   c = __shfl(e.x, t + half, 64);
            float v = __int_as_float(__shfl(e.y, t + half, 64));
            uint u = E32[c * 32 + l32];
            acc0 += v * bf_lo(u);  acc1 += v * bf_hi(u);
        }
        if (t < m) {
            int   c = __shfl(e.x, t, 64);
            float v = __int_as_float(__shfl(e.y, t, 64));
            if (half == 0) {
                uint u = E32[c * 32 + l32];
                acc0 += v * bf_lo(u);  acc1 += v * bf_hi(u);
            }
        }
    }
    acc0 += __shfl_xor(acc0, 32, 64);
    acc1 += __shfl_xor(acc1, 32, 64);
    if (half == 0)
        *(float2*)&Lout[r * D + l32 * 2] = make_float2(acc0, acc1);
}

// ---- fused transform: ego_new = leaky((L+E)@Wgc + (L*E)@Wbi + 2b) -> bf16 ----
__global__ __launch_bounds__(256) void k_transform(const ushort* __restrict__ E16,
                                                   const float* __restrict__ L,
                                                   const float* __restrict__ Wgc,
                                                   const float* __restrict__ Wbi,
                                                   const float* __restrict__ bb,
                                                   ushort* __restrict__ O16, int n) {
    __shared__ float xT[2 * D][D];
    __shared__ float W2[2 * D][D];
    int tid = threadIdx.x;
    int rowbase = blockIdx.x * 64;

    for (int i = tid; i < 128 * 16; i += 256) {
        int k = i >> 4, q = i & 15;
        const float* src = (k < D) ? (Wgc + k * D + q * 4) : (Wbi + (k - D) * D + q * 4);
        *(float4*)&W2[k][q * 4] = *(const float4*)src;
    }
    {
        int row = tid >> 2;
        int cg  = (tid & 3) * 16;
        int r   = rowbase + row;
        for (int j = 0; j < 4; ++j) {
            int c = cg + j * 4;
            float4 l = make_float4(0, 0, 0, 0);
            uint2  eu = make_uint2(0, 0);
            if (r < n) {
                l  = *(const float4*)&L[r * D + c];
                eu = *(const uint2*)&E16[r * D + c];
            }
            float e0 = bf_lo(eu.x), e1 = bf_hi(eu.x), e2 = bf_lo(eu.y), e3 = bf_hi(eu.y);
            xT[c + 0][row] = l.x + e0;  xT[D + c + 0][row] = l.x * e0;
            xT[c + 1][row] = l.y + e1;  xT[D + c + 1][row] = l.y * e1;
            xT[c + 2][row] = l.z + e2;  xT[D + c + 2][row] = l.z * e2;
            xT[c + 3][row] = l.w + e3;  xT[D + c + 3][row] = l.w * e3;
        }
    }
    __syncthreads();

    int tx = tid & 15, ty = tid >> 4;
    float acc[4][4];
    #pragma unroll
    for (int i = 0; i < 4; ++i)
        #pragma unroll
        for (int j = 0; j < 4; ++j) acc[i][j] = 0.f;

    #pragma unroll 4
    for (int k = 0; k < 2 * D; ++k) {
        float4 a = *(const float4*)&xT[k][ty * 4];
        float4 b = *(const float4*)&W2[k][tx * 4];
        float av[4] = {a.x, a.y, a.z, a.w};
        float bv[4] = {b.x, b.y, b.z, b.w};
        #pragma unroll
        for (int i = 0; i < 4; ++i)
            #pragma unroll
            for (int j = 0; j < 4; ++j) acc[i][j] += av[i] * bv[j];
    }

    float4 bias = *(const float4*)&bb[tx * 4];
    float bv[4] = {bias.x, bias.y, bias.z, bias.w};
    #pragma unroll
    for (int i = 0; i < 4; ++i) {
        int r = rowbase + ty * 4 + i;
        if (r < n) {
            float o[4];
            #pragma unroll
            for (int j = 0; j < 4; ++j) {
                float y = acc[i][j] + 2.f * bv[j];
                o[j] = (y >= 0.f) ? y : NEG_SLOPE * y;
            }
            uint lo = bf16rne(o[0]) | (bf16rne(o[1]) << 16);
            uint hi = bf16rne(o[2]) | (bf16rne(o[3]) << 16);
            *(uint2*)&O16[r * D + tx * 4] = make_uint2(lo, hi);
        }
    }
}

// ---------------- gathers into output ----------------
__global__ void k_gather0(const float* __restrict__ u, const float* __restrict__ it,
                          const int* __restrict__ users, const int* __restrict__ pos,
                          const int* __restrict__ neg, float* __restrict__ out) {
    int lane = threadIdx.x & 63;
    int gi = blockIdx.x * 4 + (threadIdx.x >> 6);
    int g = gi >> 12, b = gi & 4095;
    const float* src = (g == 0) ? (u + (size_t)users[b] * D)
                                : (it + (size_t)((g == 1) ? pos[b] : neg[b]) * D);
    out[gi * 256 + lane] = src[lane];
}

__global__ void k_gathern(const ushort* __restrict__ E16, const int* __restrict__ users,
                          const int* __restrict__ pos, const int* __restrict__ neg,
                          float* __restrict__ out, int layer) {
    int lane = threadIdx.x & 63;
    int gi = blockIdx.x * 4 + (threadIdx.x >> 6);
    int g = gi >> 12, b = gi & 4095;
    int src = (g == 0) ? users[b] : (N_USER + ((g == 1) ? pos[b] : neg[b]));
    float v = __uint_as_float(((uint)E16[src * D + lane]) << 16);
    float ss = v * v;
    #pragma unroll
    for (int off = 32; off >= 1; off >>= 1) ss += __shfl_xor(ss, off, 64);
    float dnm = fmaxf(sqrtf(ss), 1e-12f);
    out[gi * 256 + layer * D + lane] = v / dnm;
}

extern "C" void kernel_launch(void* const* d_in, const int* in_sizes, int n_in,
                              void* d_out, int out_size, void* d_ws, size_t ws_size,
                              hipStream_t stream) {
    const float* user_emb = (const float*)d_in[0];
    const float* item_emb = (const float*)d_in[1];
    const float* W_gc     = (const float*)d_in[2];
    const float* W_bi     = (const float*)d_in[3];
    const float* b_bi     = (const float*)d_in[4];
    const float* vals     = (const float*)d_in[5];
    const int*   rows     = (const int*)d_in[6];
    const int*   cols     = (const int*)d_in[7];
    const int*   users    = (const int*)d_in[8];
    const int*   pos      = (const int*)d_in[9];
    const int*   neg      = (const int*)d_in[10];
    float* out = (float*)d_out;

    char* ws = (char*)d_ws;
    size_t off = 0;
    auto alloc = [&](size_t b) { void* p = ws + off; off += (b + 255) & ~(size_t)255; return p; };
    ushort* Ea  = (ushort*)alloc((size_t)NTOT * D * 2);   // bf16 ego (ping)
    ushort* Eb  = (ushort*)alloc((size_t)NTOT * D * 2);   // bf16 ego (pong)
    float*  L   = (float*) alloc((size_t)NTOT * D * 4);   // f32 spmm output
    int2*   csr = (int2*)  alloc((size_t)NNZ * 8);
    int*    ptr = (int*)   alloc((size_t)(NTOT + 1) * 4);
    int*    bptr= (int*)   alloc((NB + 1) * 4);
    int*    bcnt= (int*)   alloc(NB * 4);
    int*    bcur= (int*)   alloc(NB * 4);
    int2*   bucketed = (int2*)L;   // alias: dead before first spmm writes L
    (void)ws_size;

    hipLaunchKernelGGL(k_concat16, dim3(9375), dim3(256),  0, stream, user_emb, item_emb, Ea);
    hipLaunchKernelGGL(k_bzero,    dim3(1),    dim3(256),  0, stream, bcnt);
    hipLaunchKernelGGL(k_bhist,    dim3(NB),   dim3(1024), 0, stream, rows, bcnt);
    hipLaunchKernelGGL(k_bscan,    dim3(1),    dim3(256),  0, stream, bcnt, bptr, bcur);
    hipLaunchKernelGGL(k_binpass1, dim3(NB),   dim3(1024), 0, stream, rows, cols, vals, bcur, bucketed);
    hipLaunchKernelGGL(k_binpass2, dim3(NB),   dim3(1024), 0, stream, bptr, bucketed, ptr, csr);
    hipLaunchKernelGGL(k_gather0,  dim3(3072), dim3(256),  0, stream, user_emb, item_emb, users, pos, neg, out);

    ushort* cur = Ea; ushort* nxt = Eb;
    for (int k = 0; k < 3; ++k) {
        hipLaunchKernelGGL(k_spmm,      dim3(37500), dim3(256), 0, stream, ptr, csr, cur, L);
        hipLaunchKernelGGL(k_transform, dim3(2344),  dim3(256), 0, stream, cur, L,
                           W_gc + k * 4096, W_bi + k * 4096, b_bi + k * 64, nxt, NTOT);
        hipLaunchKernelGGL(k_gathern,   dim3(3072),  dim3(256), 0, stream, nxt, users, pos, neg, out, k + 1);
        ushort* t = cur; cur = nxt; nxt = t;
    }
}

// Round 4
// 542.967 us; speedup vs baseline: 1.5075x; 1.0285x over previous
//
#include <hip/hip_runtime.h>

#define N_USER 50000
#define N_ITEM 100000
#define NTOT   150000
#define D      64
#define NNZ    2400000
#define NEG_SLOPE 0.01f

#define BSHIFT 10
#define NB     147            // ceil(NTOT / 1024)
#define P1_PER 4096           // entries per block in binning passes (1024 thr x 4)
#define NBLK1  586            // ceil(NNZ / P1_PER)

typedef unsigned int uint;
typedef unsigned short ushort;

__device__ inline uint bf16rne(float x) {           // f32 -> bf16 bits (RNE)
    uint b = __float_as_uint(x);
    return (b + 0x7FFFu + ((b >> 16) & 1u)) >> 16;
}
__device__ inline float bf_lo(uint u) { return __uint_as_float(u << 16); }
__device__ inline float bf_hi(uint u) { return __uint_as_float(u & 0xFFFF0000u); }

// ---------------- concat user+item embeddings -> bf16 ego0 ----------------
__global__ void k_concat16(const float* __restrict__ u, const float* __restrict__ it,
                           ushort* __restrict__ A16) {
    int i = blockIdx.x * 256 + threadIdx.x;          // float4 index, exact grid 2.4M
    const int nu4 = N_USER * D / 4;
    float4 v = (i < nu4) ? ((const float4*)u)[i] : ((const float4*)it)[i - nu4];
    uint lo = bf16rne(v.x) | (bf16rne(v.y) << 16);
    uint hi = bf16rne(v.z) | (bf16rne(v.w) << 16);
    ((uint2*)A16)[i] = make_uint2(lo, hi);
}

__global__ void k_bzero(int* __restrict__ bcnt) {
    int t = threadIdx.x;
    if (t < NB) bcnt[t] = 0;
}

// ---------------- bucket histogram (LDS-aggregated) ----------------
__global__ __launch_bounds__(1024) void k_bhist(const int* __restrict__ rows,
                                                int* __restrict__ bcnt) {
    __shared__ int lcnt[NB];
    int tid = threadIdx.x;
    if (tid < NB) lcnt[tid] = 0;
    __syncthreads();
    int base = blockIdx.x * P1_PER;
    #pragma unroll
    for (int k = 0; k < 4; ++k) {
        int i = base + k * 1024 + tid;
        if (i < NNZ) atomicAdd(&lcnt[rows[i] >> BSHIFT], 1);
    }
    __syncthreads();
    if (tid < NB) atomicAdd(&bcnt[tid], lcnt[tid]);
}

__global__ void k_bscan(const int* __restrict__ bcnt, int* __restrict__ bptr,
                        int* __restrict__ bcur) {
    __shared__ int s[256];
    int tid = threadIdx.x;
    int v = (tid < NB) ? bcnt[tid] : 0;
    s[tid] = v; __syncthreads();
    for (int off = 1; off < 256; off <<= 1) {
        int t = (tid >= off) ? s[tid - off] : 0;
        __syncthreads();
        s[tid] += t;
        __syncthreads();
    }
    if (tid < NB) { int ex = s[tid] - v; bptr[tid] = ex; bcur[tid] = ex; }
    if (tid == NB - 1) bptr[NB] = s[tid];
}

// ---------------- pass 1: bin entries bucket-major ----------------
__global__ __launch_bounds__(1024) void k_binpass1(const int* __restrict__ rows,
                                                   const int* __restrict__ cols,
                                                   const float* __restrict__ vals,
                                                   int* __restrict__ bcur,
                                                   int2* __restrict__ bucketed) {
    __shared__ int lcnt[NB], lbase[NB];
    int tid = threadIdx.x;
    int base = blockIdx.x * P1_PER;
    if (tid < NB) lcnt[tid] = 0;
    __syncthreads();
    int r[4];
    #pragma unroll
    for (int k = 0; k < 4; ++k) {
        int i = base + k * 1024 + tid;
        r[k] = (i < NNZ) ? rows[i] : -1;
        if (r[k] >= 0) atomicAdd(&lcnt[r[k] >> BSHIFT], 1);
    }
    __syncthreads();
    if (tid < NB) { lbase[tid] = atomicAdd(&bcur[tid], lcnt[tid]); lcnt[tid] = 0; }
    __syncthreads();
    #pragma unroll
    for (int k = 0; k < 4; ++k) {
        int i = base + k * 1024 + tid;
        if (r[k] >= 0) {
            int b = r[k] >> BSHIFT;
            int off = atomicAdd(&lcnt[b], 1);
            bucketed[lbase[b] + off] =
                make_int2(((r[k] & 1023) << 18) | cols[i], __float_as_int(vals[i]));
        }
    }
}

// ---------------- pass 2: per-bucket CSR build ----------------
__global__ __launch_bounds__(1024) void k_binpass2(const int* __restrict__ bptr,
                                                   const int2* __restrict__ bucketed,
                                                   int* __restrict__ ptr,
                                                   int2* __restrict__ csr) {
    __shared__ int c0[1024], px[1024];
    int tid = threadIdx.x, b = blockIdx.x;
    int s = bptr[b], e = bptr[b + 1];
    c0[tid] = 0;
    __syncthreads();
    for (int i = s + tid; i < e; i += 1024) atomicAdd(&c0[bucketed[i].x >> 18], 1);
    __syncthreads();
    int v = c0[tid];
    px[tid] = v;
    __syncthreads();
    for (int off = 1; off < 1024; off <<= 1) {
        int t = (tid >= off) ? px[tid - off] : 0;
        __syncthreads();
        px[tid] += t;
        __syncthreads();
    }
    int ex = px[tid] - v;
    int r = (b << BSHIFT) + tid;
    if (r <= NTOT) ptr[r] = s + ex;
    px[tid] = ex;
    c0[tid] = 0;
    __syncthreads();
    for (int i = s + tid; i < e; i += 1024) {
        int2 e2 = bucketed[i];
        int lr = e2.x >> 18;
        int off = atomicAdd(&c0[lr], 1);
        csr[s + px[lr] + off] = make_int2(e2.x & 0x3FFFF, e2.y);
    }
}

// -------- SpMM: wave/row, scalar CSR broadcast, 8 entries/iter, bf16 gathers --------
__global__ __launch_bounds__(256) void k_spmm(const int* __restrict__ ptr,
                                              const int2* __restrict__ csr,
                                              const ushort* __restrict__ E16,
                                              float* __restrict__ Lout) {
    int lane = threadIdx.x & 63;
    int half = lane >> 5;
    int l32  = lane & 31;
    int r = __builtin_amdgcn_readfirstlane(blockIdx.x * 4 + (threadIdx.x >> 6));
    int start = ptr[r], end = ptr[r + 1];
    float acc0 = 0.f, acc1 = 0.f;
    const uint* E32 = (const uint*)E16;              // [c*32 + l32] = cols (2*l32, 2*l32+1)
    int j = start;
    for (; j + 7 < end; j += 8) {                    // 8 entries: 4 gather-lines in flight
        int2 ea = csr[j + 0], eb = csr[j + 1];       // uniform -> scalar loads
        int2 ec = csr[j + 2], ed = csr[j + 3];
        int2 ee = csr[j + 4], ef = csr[j + 5];
        int2 eg = csr[j + 6], eh = csr[j + 7];
        int c0 = half ? eb.x : ea.x;
        int c1 = half ? ed.x : ec.x;
        int c2 = half ? ef.x : ee.x;
        int c3 = half ? eh.x : eg.x;
        uint u0 = E32[(c0 << 5) + l32];
        uint u1 = E32[(c1 << 5) + l32];
        uint u2 = E32[(c2 << 5) + l32];
        uint u3 = E32[(c3 << 5) + l32];
        float v0 = __int_as_float(half ? eb.y : ea.y);
        float v1 = __int_as_float(half ? ed.y : ec.y);
        float v2 = __int_as_float(half ? ef.y : ee.y);
        float v3 = __int_as_float(half ? eh.y : eg.y);
        acc0 += v0 * bf_lo(u0);  acc1 += v0 * bf_hi(u0);
        acc0 += v1 * bf_lo(u1);  acc1 += v1 * bf_hi(u1);
        acc0 += v2 * bf_lo(u2);  acc1 += v2 * bf_hi(u2);
        acc0 += v3 * bf_lo(u3);  acc1 += v3 * bf_hi(u3);
    }
    for (; j + 1 < end; j += 2) {
        int2 ea = csr[j], eb = csr[j + 1];
        int c   = half ? eb.x : ea.x;
        float v = __int_as_float(half ? eb.y : ea.y);
        uint u = E32[(c << 5) + l32];
        acc0 += v * bf_lo(u);  acc1 += v * bf_hi(u);
    }
    if (j < end) {
        int2 ea = csr[j];
        if (half == 0) {
            uint u = E32[(ea.x << 5) + l32];
            float v = __int_as_float(ea.y);
            acc0 += v * bf_lo(u);  acc1 += v * bf_hi(u);
        }
    }
    acc0 += __shfl_xor(acc0, 32, 64);
    acc1 += __shfl_xor(acc1, 32, 64);
    if (half == 0)
        *(float2*)&Lout[r * D + l32 * 2] = make_float2(acc0, acc1);
}

// ---- fused transform: ego_new = leaky((L+E)@Wgc + (L*E)@Wbi + 2b) -> bf16 ----
__global__ __launch_bounds__(256) void k_transform(const ushort* __restrict__ E16,
                                                   const float* __restrict__ L,
                                                   const float* __restrict__ Wgc,
                                                   const float* __restrict__ Wbi,
                                                   const float* __restrict__ bb,
                                                   ushort* __restrict__ O16, int n) {
    __shared__ float xT[2 * D][D];
    __shared__ float W2[2 * D][D];
    int tid = threadIdx.x;
    int rowbase = blockIdx.x * 64;

    for (int i = tid; i < 128 * 16; i += 256) {
        int k = i >> 4, q = i & 15;
        const float* src = (k < D) ? (Wgc + k * D + q * 4) : (Wbi + (k - D) * D + q * 4);
        *(float4*)&W2[k][q * 4] = *(const float4*)src;
    }
    {
        int row = tid >> 2;
        int cg  = (tid & 3) * 16;
        int r   = rowbase + row;
        for (int j = 0; j < 4; ++j) {
            int c = cg + j * 4;
            float4 l = make_float4(0, 0, 0, 0);
            uint2  eu = make_uint2(0, 0);
            if (r < n) {
                l  = *(const float4*)&L[r * D + c];
                eu = *(const uint2*)&E16[r * D + c];
            }
            float e0 = bf_lo(eu.x), e1 = bf_hi(eu.x), e2 = bf_lo(eu.y), e3 = bf_hi(eu.y);
            xT[c + 0][row] = l.x + e0;  xT[D + c + 0][row] = l.x * e0;
            xT[c + 1][row] = l.y + e1;  xT[D + c + 1][row] = l.y * e1;
            xT[c + 2][row] = l.z + e2;  xT[D + c + 2][row] = l.z * e2;
            xT[c + 3][row] = l.w + e3;  xT[D + c + 3][row] = l.w * e3;
        }
    }
    __syncthreads();

    int tx = tid & 15, ty = tid >> 4;
    float acc[4][4];
    #pragma unroll
    for (int i = 0; i < 4; ++i)
        #pragma unroll
        for (int j = 0; j < 4; ++j) acc[i][j] = 0.f;

    #pragma unroll 4
    for (int k = 0; k < 2 * D; ++k) {
        float4 a = *(const float4*)&xT[k][ty * 4];
        float4 b = *(const float4*)&W2[k][tx * 4];
        float av[4] = {a.x, a.y, a.z, a.w};
        float bv[4] = {b.x, b.y, b.z, b.w};
        #pragma unroll
        for (int i = 0; i < 4; ++i)
            #pragma unroll
            for (int j = 0; j < 4; ++j) acc[i][j] += av[i] * bv[j];
    }

    float4 bias = *(const float4*)&bb[tx * 4];
    float bv[4] = {bias.x, bias.y, bias.z, bias.w};
    #pragma unroll
    for (int i = 0; i < 4; ++i) {
        int r = rowbase + ty * 4 + i;
        if (r < n) {
            float o[4];
            #pragma unroll
            for (int j = 0; j < 4; ++j) {
                float y = acc[i][j] + 2.f * bv[j];
                o[j] = (y >= 0.f) ? y : NEG_SLOPE * y;
            }
            uint lo = bf16rne(o[0]) | (bf16rne(o[1]) << 16);
            uint hi = bf16rne(o[2]) | (bf16rne(o[3]) << 16);
            *(uint2*)&O16[r * D + tx * 4] = make_uint2(lo, hi);
        }
    }
}

// ---------------- gathers into output ----------------
__global__ void k_gather0(const float* __restrict__ u, const float* __restrict__ it,
                          const int* __restrict__ users, const int* __restrict__ pos,
                          const int* __restrict__ neg, float* __restrict__ out) {
    int lane = threadIdx.x & 63;
    int gi = blockIdx.x * 4 + (threadIdx.x >> 6);
    int g = gi >> 12, b = gi & 4095;
    const float* src = (g == 0) ? (u + (size_t)users[b] * D)
                                : (it + (size_t)((g == 1) ? pos[b] : neg[b]) * D);
    out[gi * 256 + lane] = src[lane];
}

__global__ void k_gathern(const ushort* __restrict__ E16, const int* __restrict__ users,
                          const int* __restrict__ pos, const int* __restrict__ neg,
                          float* __restrict__ out, int layer) {
    int lane = threadIdx.x & 63;
    int gi = blockIdx.x * 4 + (threadIdx.x >> 6);
    int g = gi >> 12, b = gi & 4095;
    int src = (g == 0) ? users[b] : (N_USER + ((g == 1) ? pos[b] : neg[b]));
    float v = __uint_as_float(((uint)E16[src * D + lane]) << 16);
    float ss = v * v;
    #pragma unroll
    for (int off = 32; off >= 1; off >>= 1) ss += __shfl_xor(ss, off, 64);
    float dnm = fmaxf(sqrtf(ss), 1e-12f);
    out[gi * 256 + layer * D + lane] = v / dnm;
}

extern "C" void kernel_launch(void* const* d_in, const int* in_sizes, int n_in,
                              void* d_out, int out_size, void* d_ws, size_t ws_size,
                              hipStream_t stream) {
    const float* user_emb = (const float*)d_in[0];
    const float* item_emb = (const float*)d_in[1];
    const float* W_gc     = (const float*)d_in[2];
    const float* W_bi     = (const float*)d_in[3];
    const float* b_bi     = (const float*)d_in[4];
    const float* vals     = (const float*)d_in[5];
    const int*   rows     = (const int*)d_in[6];
    const int*   cols     = (const int*)d_in[7];
    const int*   users    = (const int*)d_in[8];
    const int*   pos      = (const int*)d_in[9];
    const int*   neg      = (const int*)d_in[10];
    float* out = (float*)d_out;

    char* ws = (char*)d_ws;
    size_t off = 0;
    auto alloc = [&](size_t b) { void* p = ws + off; off += (b + 255) & ~(size_t)255; return p; };
    ushort* Ea  = (ushort*)alloc((size_t)NTOT * D * 2);   // bf16 ego (ping)
    ushort* Eb  = (ushort*)alloc((size_t)NTOT * D * 2);   // bf16 ego (pong)
    float*  L   = (float*) alloc((size_t)NTOT * D * 4);   // f32 spmm output
    int2*   csr = (int2*)  alloc((size_t)NNZ * 8);
    int*    ptr = (int*)   alloc((size_t)(NTOT + 1) * 4);
    int*    bptr= (int*)   alloc((NB + 1) * 4);
    int*    bcnt= (int*)   alloc(NB * 4);
    int*    bcur= (int*)   alloc(NB * 4);
    int2*   bucketed = (int2*)L;   // alias: dead before first spmm writes L
    (void)ws_size;

    hipLaunchKernelGGL(k_concat16, dim3(9375), dim3(256),  0, stream, user_emb, item_emb, Ea);
    hipLaunchKernelGGL(k_bzero,    dim3(1),    dim3(256),  0, stream, bcnt);
    hipLaunchKernelGGL(k_bhist,    dim3(NBLK1),dim3(1024), 0, stream, rows, bcnt);
    hipLaunchKernelGGL(k_bscan,    dim3(1),    dim3(256),  0, stream, bcnt, bptr, bcur);
    hipLaunchKernelGGL(k_binpass1, dim3(NBLK1),dim3(1024), 0, stream, rows, cols, vals, bcur, bucketed);
    hipLaunchKernelGGL(k_binpass2, dim3(NB),   dim3(1024), 0, stream, bptr, bucketed, ptr, csr);
    hipLaunchKernelGGL(k_gather0,  dim3(3072), dim3(256),  0, stream, user_emb, item_emb, users, pos, neg, out);

    ushort* cur = Ea; ushort* nxt = Eb;
    for (int k = 0; k < 3; ++k) {
        hipLaunchKernelGGL(k_spmm,      dim3(37500), dim3(256), 0, stream, ptr, csr, cur, L);
        hipLaunchKernelGGL(k_transform, dim3(2344),  dim3(256), 0, stream, cur, L,
                           W_gc + k * 4096, W_bi + k * 4096, b_bi + k * 64, nxt, NTOT);
        hipLaunchKernelGGL(k_gathern,   dim3(3072),  dim3(256), 0, stream, nxt, users, pos, neg, out, k + 1);
        ushort* t = cur; cur = nxt; nxt = t;
    }
}